// Round 12
// baseline (966.473 us; speedup 1.0000x reference)
//
#include <hip/hip_runtime.h>
#include <cstdint>

#define BLK 256
#define ABLK 512           // agg kernels: 8 waves/block
#define BBLK 1024          // bucket: 16 waves/block (R7 lesson: occupancy must
                           // come from BLK, not grid — batching needs CHUNK>>NS)
#define EJ 4
#define CHUNK (BBLK * EJ)  // 4096 edges per bucket block, grid 391
#define SLB 6              // slice = 64 nodes
#define SLN 64
#define SCAP 1536          // mean 1024 @ E=1.6M/NS=1563; +16 sigma; 128-aligned
#define NSMAX 1600         // n <= 102400 supported

typedef __attribute__((ext_vector_type(8))) short bf16x8;
typedef __attribute__((ext_vector_type(4))) float f32x4;

__device__ inline unsigned short f2bf(float f) {  // RNE
  unsigned u = __float_as_uint(f);
  return (unsigned short)((u + 0x7FFF + ((u >> 16) & 1)) >> 16);
}
__device__ inline float bflo(unsigned u) { return __uint_as_float(u << 16); }
__device__ inline float bfhi(unsigned u) { return __uint_as_float(u & 0xFFFF0000u); }

// Native LDS float atomic add via inline asm (R10 lesson: hipcc lowers
// atomicAdd(float*)/unsafeAtomicAdd on LDS to a CAS retry loop (R1: 9x stall);
// HW ds_add_f32 is fire-and-forget at ds_add_u32 cost. Low 32 bits of a
// flat-cast shared pointer = LDS byte offset.)
__device__ inline unsigned ldsoff(const void* p) {
  return (unsigned)(uintptr_t)p;
}

// R11 lesson (correctness race): asm DS ops are INVISIBLE to the compiler's
// waitcnt tracker, so __syncthreads() may emit s_barrier with NO lgkmcnt
// drain -> other waves read accumulators before fire-and-forget adds land
// (non-deterministic absmax 0.109/468). The HW lgkmcnt counter DOES include
// asm DS ops, so an explicit drain before the barrier fixes it.
__device__ inline void ldsDrain() {
  asm volatile("s_waitcnt lgkmcnt(0)" ::: "memory");
  __builtin_amdgcn_sched_barrier(0);
}

// ---------------- init per-slice cursors to slice base ----------------
__global__ __launch_bounds__(BLK) void k_zeroC(int* __restrict__ cur, int NS) {
  int s = blockIdx.x * BLK + threadIdx.x;
  if (s < NS) cur[s] = s * SCAP;
}

// ---------------- bucket edges into fixed-capacity slice bins ----------------
// LDS histogram -> one batched reservation per (block,slice) -> LDS-cursor
// scatter. Single LDS array: c[s] is count, then global base, then cursor.
// 16 waves/block so the scattered 8B stores have TLP to hide under.
// bpk[p] = { (dstLocal<<20) | src, ew }   (requires n <= 2^20, dstLocal < 64)
__global__ __launch_bounds__(BBLK) void k_bucket(const int* __restrict__ src,
                                                 const int* __restrict__ dst,
                                                 const float* __restrict__ ew,
                                                 int* __restrict__ cur,
                                                 int2* __restrict__ bpk,
                                                 int n, int E, int NS) {
  __shared__ int c[NSMAX];
  int tid = threadIdx.x;
  for (int i = tid; i < NS; i += BBLK) c[i] = 0;
  __syncthreads();
  int base = blockIdx.x * CHUNK;
  int dloc[EJ];
#pragma unroll
  for (int j = 0; j < EJ; j++) {
    int idx = base + j * BBLK + tid;
    int d = -1;
    if (idx < E) {
      d = dst[idx];
      if ((unsigned)d >= (unsigned)n) d = -1;
    }
    dloc[j] = d;
    if (d >= 0) atomicAdd(&c[d >> SLB], 1);
  }
  __syncthreads();
  for (int s = tid; s < NS; s += BBLK) {
    int cc = c[s];
    if (cc) c[s] = atomicAdd(&cur[s], cc);  // c[s] becomes this block's cursor
  }
  __syncthreads();
#pragma unroll
  for (int j = 0; j < EJ; j++) {
    int idx = base + j * BBLK + tid;
    int d = dloc[j];
    if (d >= 0) {
      int s = d >> SLB;
      int p = atomicAdd(&c[s], 1);
      p = min(max(p, s * SCAP), (s + 1) * SCAP - 1);  // clamp into slice
      int packed = ((d & (SLN - 1)) << 20) | (src[idx] & 0xFFFFF);
      bpk[p] = make_int2(packed, __float_as_int(ew[idx]));
    }
  }
}

// ---------------- per-slice weighted in-degree -> dinv; pad slices ----------
// Pads each slice's edge list to a multiple of 128 with {0,0} dummies
// (dl=0, w=0 -> contributes nothing) so agg loops run maskless/clampless.
__global__ __launch_bounds__(BLK) void k_dinv(int2* __restrict__ bpk,
                                              int* __restrict__ cur,
                                              float* __restrict__ dinv, int n) {
  __shared__ float wsum[SLN];
  int s = blockIdx.x, tid = threadIdx.x;
  int node0 = s << SLB;
  int e0 = s * SCAP;
  int cnt = min(cur[s], e0 + SCAP) - e0;
  int cntP = min((cnt + 127) & ~127, SCAP);  // SCAP is 128-aligned
  if (tid < SLN) wsum[tid] = 0.f;
  for (int e = cnt + tid; e < cntP; e += BLK) bpk[e0 + e] = make_int2(0, 0);
  if (tid == 0) cur[s] = e0 + cntP;
  __syncthreads();
  for (int e = e0 + tid; e < e0 + cnt; e += BLK) {
    int2 pk = bpk[e];
    unsigned a = ldsoff(&wsum[(unsigned)pk.x >> 20]);
    float w = __int_as_float(pk.y);
    asm volatile("ds_add_f32 %0, %1" :: "v"(a), "v"(w) : "memory");
  }
  ldsDrain();
  __syncthreads();
  if (tid < SLN && node0 + tid < n)
    dinv[node0 + tid] = rsqrtf(1.0f + wsum[tid]);  // deg >= 1 (self loop)
}

// ---------------- GEMM1 (MFMA bf16x3): h1s = dinv * (x @ W1), fp32-faithful --
// bf16x3 split: x=xh+xl, W=Wh+Wl; h ~= xh@Wh + xl@Wh + xh@Wl (residual ~2^-17
// rel). Block = 64 rows x 64 cols, 4 waves x 16 rows, K=128 = 4 ksteps.
// Frag layout (m89/m97-verified): A/B lane&15 = row/col, 8 k-contig at
// (lane>>4)*8; C/D col=lane&15, row=(lane>>4)*4+reg.
__device__ inline void splitpk(float a, float b, unsigned& h, unsigned& l) {
  unsigned short ha = f2bf(a), hb = f2bf(b);
  h = (unsigned)ha | ((unsigned)hb << 16);
  float ra = a - __uint_as_float((unsigned)ha << 16);
  float rb = b - __uint_as_float((unsigned)hb << 16);
  l = (unsigned)f2bf(ra) | ((unsigned)f2bf(rb) << 16);
}

__global__ __launch_bounds__(BLK) void k_gemm1(const float* __restrict__ x,
                                               const float* __restrict__ W,
                                               const float* __restrict__ dinv,
                                               unsigned* __restrict__ h1s, int n) {
  __shared__ unsigned Wh[4][4][64][4];  // [kstep][coltile][lane][dword]
  __shared__ unsigned Wl[4][4][64][4];
  int tid = threadIdx.x;
  for (int i = tid; i < 4096; i += BLK) {
    int dw = i & 3, lane = (i >> 2) & 63, ct = (i >> 8) & 3, ks = i >> 10;
    int col = ct * 16 + (lane & 15);
    int kb = ks * 32 + ((lane >> 4) << 3) + dw * 2;
    unsigned h, l;
    splitpk(W[kb * 64 + col], W[(kb + 1) * 64 + col], h, l);
    Wh[ks][ct][lane][dw] = h;
    Wl[ks][ct][lane][dw] = l;
  }
  __syncthreads();

  int w = tid >> 6, l = tid & 63;
  int rowA = blockIdx.x * 64 + w * 16 + (l & 15);    // row this lane LOADS
  int rowAc = min(rowA, n - 1);
  int kg = l >> 4;
  const float4* xr = (const float4*)(x + (size_t)rowAc * 128);

  f32x4 acc[4];
#pragma unroll
  for (int ct = 0; ct < 4; ct++) acc[ct] = (f32x4){0.f, 0.f, 0.f, 0.f};

  union Frag { unsigned u[4]; bf16x8 s; };
#pragma unroll
  for (int ks = 0; ks < 4; ks++) {
    float4 f0 = xr[ks * 8 + kg * 2];
    float4 f1 = xr[ks * 8 + kg * 2 + 1];
    Frag Ah, Al;
    splitpk(f0.x, f0.y, Ah.u[0], Al.u[0]);
    splitpk(f0.z, f0.w, Ah.u[1], Al.u[1]);
    splitpk(f1.x, f1.y, Ah.u[2], Al.u[2]);
    splitpk(f1.z, f1.w, Ah.u[3], Al.u[3]);
#pragma unroll
    for (int ct = 0; ct < 4; ct++) {
      Frag Bh, Bl;
      *(uint4*)Bh.u = *(const uint4*)Wh[ks][ct][l];
      *(uint4*)Bl.u = *(const uint4*)Wl[ks][ct][l];
      acc[ct] = __builtin_amdgcn_mfma_f32_16x16x32_bf16(Ah.s, Bh.s, acc[ct], 0, 0, 0);
      acc[ct] = __builtin_amdgcn_mfma_f32_16x16x32_bf16(Al.s, Bh.s, acc[ct], 0, 0, 0);
      acc[ct] = __builtin_amdgcn_mfma_f32_16x16x32_bf16(Ah.s, Bl.s, acc[ct], 0, 0, 0);
    }
  }

  // epilogue: lane owns col = ct*16 + (l&15), rows (l>>4)*4 + r
  int rbase = blockIdx.x * 64 + w * 16 + (l >> 4) * 4;
  float di[4];
#pragma unroll
  for (int r = 0; r < 4; r++) di[r] = dinv[min(rbase + r, n - 1)];
  int cl = l & 15;
#pragma unroll
  for (int ct = 0; ct < 4; ct++) {
#pragma unroll
    for (int r = 0; r < 4; r++) {
      float v = acc[ct][r] * di[r];
      float vp = __shfl_xor(v, 1, 64);
      if ((cl & 1) == 0 && rbase + r < n)
        h1s[(size_t)(rbase + r) * 32 + ct * 8 + (cl >> 1)] =
            (unsigned)f2bf(v) | ((unsigned)f2bf(vp) << 16);
    }
  }
}

// ---------------- layer-1: slice-LDS aggregate + bias + ReLU + GEMM2 --------
// Block = slice of 64 nodes, 512 threads. 16 lanes/edge, lane owns a
// dword-pair (uint2 gather); maskless (slices 128-padded by k_dinv).
// Float LDS accumulators via native ds_add_f32 (inline asm) — kills the
// fixed-point cvt chain; offset:4 immediates fold +1 addressing. Explicit
// lgkmcnt drain before barrier (R11 race lesson). Stride 33, two planes.
#define U1 8
__global__ __launch_bounds__(ABLK) void k_agg1s(const float* __restrict__ dinv,
                                                const int2* __restrict__ bpk,
                                                const int* __restrict__ cur,
                                                const unsigned* __restrict__ h1s,
                                                const float* __restrict__ b1,
                                                const float* __restrict__ W2,
                                                unsigned* __restrict__ h2s, int n) {
  __shared__ float accE[SLN * 33];
  __shared__ float accO[SLN * 33];
  __shared__ float W2s[64 * 16];
  __shared__ float dv[SLN];
  __shared__ float bb[64];
  int tid = threadIdx.x;
  int s = blockIdx.x;
  int node0 = s << SLB;
  int sn = min(SLN, n - node0);
  for (int i = tid; i < SLN * 33; i += ABLK) { accE[i] = 0.f; accO[i] = 0.f; }
  for (int i = tid; i < 1024; i += ABLK) W2s[i] = W2[i];
  if (tid < SLN) dv[tid] = (tid < sn) ? dinv[node0 + tid] : 0.f;
  if (tid < 64) bb[tid] = b1[tid];
  int e0 = s * SCAP;
  int cnt = min(cur[s], e0 + SCAP) - e0;  // multiple of 128 (padded)
  __syncthreads();

  int w = tid >> 6;         // wave 0..7
  int g4 = (tid >> 4) & 3;  // edge sub-slot within wave
  int l = tid & 15;         // owns dwords 2l, 2l+1 (features 4l..4l+3)
  const unsigned* hp = h1s + 2 * l;
  unsigned baseE = ldsoff(&accE[2 * l]);
  unsigned baseO = ldsoff(&accO[2 * l]);
  for (int base = w * 32; base < cnt; base += 256) {  // 32 edges/wave-iter
    int2 pk[U1];
#pragma unroll
    for (int u = 0; u < U1; u++) pk[u] = bpk[e0 + base + g4 + 4 * u];
    uint2 gg[U1];
#pragma unroll
    for (int u = 0; u < U1; u++)
      gg[u] = *(const uint2*)(hp + (size_t)(unsigned)(pk[u].x & 0xFFFFF) * 32);
#pragma unroll
    for (int u = 0; u < U1; u++) {
      unsigned dl = (unsigned)pk[u].x >> 20;
      unsigned aE = baseE + dl * 132;  // 33 floats = 132 bytes
      unsigned aO = baseO + dl * 132;
      float wt = __int_as_float(pk[u].y);
      float vEx = wt * bflo(gg[u].x), vOx = wt * bfhi(gg[u].x);
      float vEy = wt * bflo(gg[u].y), vOy = wt * bfhi(gg[u].y);
      asm volatile(
          "ds_add_f32 %0, %2\n\t"
          "ds_add_f32 %0, %3 offset:4\n\t"
          "ds_add_f32 %1, %4\n\t"
          "ds_add_f32 %1, %5 offset:4"
          :: "v"(aE), "v"(aO), "v"(vEx), "v"(vEy), "v"(vOx), "v"(vOy)
          : "memory");
    }
  }
  ldsDrain();
  __syncthreads();
  // F1: in-place relu rows: plane[k&1][node*33+(k>>1)] = relu(dv*(acc+self)+b1[k])
  for (int i = tid; i < SLN * 64; i += ABLK) {
    int node = i >> 6, k = i & 63;
    if (node < sn) {
      int v = node0 + node;
      unsigned us = h1s[(size_t)v * 32 + (k >> 1)];  // self (pre-scaled by dinv)
      float self = (k & 1) ? bfhi(us) : bflo(us);
      float* pl = (k & 1) ? accO : accE;
      int idx = node * 33 + (k >> 1);
      pl[idx] = fmaxf(dv[node] * (pl[idx] + self) + bb[k], 0.f);
    }
  }
  __syncthreads();
  // F2: GEMM2, 16 threads per node, 32 nodes per batch; h2s = dinv * (relu @ W2)
  int j = tid & 15;
  for (int nb = 0; nb < SLN; nb += 32) {
    int node = nb + (tid >> 4);  // 0..31
    float p = 0.f;
#pragma unroll
    for (int k = 0; k < 64; k++) {
      float rv = ((k & 1) ? accO : accE)[node * 33 + (k >> 1)];
      p += rv * W2s[k * 16 + j];
    }
    p *= dv[node];
    float pp = __shfl_xor(p, 1, 64);
    if (node < sn && (j & 1) == 0)
      h2s[(size_t)(node0 + node) * 8 + (j >> 1)] =
          (unsigned)f2bf(p) | ((unsigned)f2bf(pp) << 16);
  }
}

// ---------------- layer-2: slice-LDS aggregate + bias + log_softmax ---------
// 512 threads. 4 lanes/edge, lane owns dword-pair, 4-deep gather pipeline.
// Maskless. float acc via ds_add_f32 + explicit drain, stride 17.
#define U2 4
__global__ __launch_bounds__(ABLK) void k_agg2s(const float* __restrict__ dinv,
                                                const int2* __restrict__ bpk,
                                                const int* __restrict__ cur,
                                                const unsigned* __restrict__ h2s,
                                                const float* __restrict__ b2,
                                                float* __restrict__ out, int n) {
  __shared__ float acc2[SLN * 17];
  int tid = threadIdx.x;
  int s = blockIdx.x;
  int node0 = s << SLB;
  int sn = min(SLN, n - node0);
  for (int i = tid; i < SLN * 17; i += ABLK) acc2[i] = 0.f;
  int e0 = s * SCAP;
  int cnt = min(cur[s], e0 + SCAP) - e0;  // multiple of 128 (padded)
  __syncthreads();

  int w = tid >> 6;          // wave 0..7
  int eg = (tid >> 2) & 15;  // edge slot within wave
  int m = tid & 3;           // owns dwords 2m, 2m+1 (features 4m..4m+3)
  const unsigned* hp = h2s + 2 * m;
  unsigned base2 = ldsoff(&acc2[4 * m]);
  for (int base = w * 64; base < cnt; base += 512) {  // 64 edges/wave-iter
    int2 pk[U2];
#pragma unroll
    for (int u = 0; u < U2; u++) pk[u] = bpk[e0 + base + eg + 16 * u];
    uint2 gg[U2];
#pragma unroll
    for (int u = 0; u < U2; u++)
      gg[u] = *(const uint2*)(hp + (size_t)(unsigned)(pk[u].x & 0xFFFFF) * 8);
#pragma unroll
    for (int u = 0; u < U2; u++) {
      unsigned dl = (unsigned)pk[u].x >> 20;
      unsigned a = base2 + dl * 68;  // 17 floats = 68 bytes
      float wt = __int_as_float(pk[u].y);
      float v0 = wt * bflo(gg[u].x), v1 = wt * bfhi(gg[u].x);
      float v2 = wt * bflo(gg[u].y), v3 = wt * bfhi(gg[u].y);
      asm volatile(
          "ds_add_f32 %0, %1\n\t"
          "ds_add_f32 %0, %2 offset:4\n\t"
          "ds_add_f32 %0, %3 offset:8\n\t"
          "ds_add_f32 %0, %4 offset:12"
          :: "v"(a), "v"(v0), "v"(v1), "v"(v2), "v"(v3)
          : "memory");
    }
  }
  ldsDrain();
  __syncthreads();
  // finalize: 16 threads per node, 32 nodes/batch, log_softmax in 16-lane group
  int f = tid & 15;
  for (int nb = 0; nb < SLN; nb += 32) {
    int node = nb + (tid >> 4);  // 0..31
    bool ok = node < sn;
    int v = node0 + min(node, sn - 1);
    float val = 0.f;
    if (ok) {
      float di = dinv[v];
      unsigned us = h2s[(size_t)v * 8 + (f >> 1)];  // self (pre-scaled)
      float self = (f & 1) ? bfhi(us) : bflo(us);
      val = di * (acc2[node * 17 + f] + self) + b2[f];
    }
    float m2 = val;
    m2 = fmaxf(m2, __shfl_xor(m2, 1, 64));
    m2 = fmaxf(m2, __shfl_xor(m2, 2, 64));
    m2 = fmaxf(m2, __shfl_xor(m2, 4, 64));
    m2 = fmaxf(m2, __shfl_xor(m2, 8, 64));
    float ex = expf(val - m2);
    float ssum = ex;
    ssum += __shfl_xor(ssum, 1, 64);
    ssum += __shfl_xor(ssum, 2, 64);
    ssum += __shfl_xor(ssum, 4, 64);
    ssum += __shfl_xor(ssum, 8, 64);
    if (ok) out[(size_t)v * 16 + f] = val - m2 - logf(ssum);
  }
}

extern "C" void kernel_launch(void* const* d_in, const int* in_sizes, int n_in,
                              void* d_out, int out_size, void* d_ws, size_t ws_size,
                              hipStream_t stream) {
  const float* x  = (const float*)d_in[0];
  const int*   ei = (const int*)d_in[1];   // int32 [2,E]
  const float* ew = (const float*)d_in[2];
  const float* W1 = (const float*)d_in[3];
  const float* b1 = (const float*)d_in[4];
  const float* W2 = (const float*)d_in[5];
  const float* b2 = (const float*)d_in[6];
  float* out = (float*)d_out;

  int n = in_sizes[0] / 128;
  int E = in_sizes[2];
  const int* src = ei;
  const int* dst = ei + E;

  int NS = ((n - 1) >> SLB) + 1;  // 1563 for n=100k
  size_t padE = (size_t)NS * SCAP;

  char* wp = (char*)d_ws;
  auto alloc = [&](size_t bytes) -> char* {
    char* r = wp;
    wp += (bytes + 15) & ~(size_t)15;
    return r;
  };
  int*      cur  = (int*)alloc((size_t)(NS + 4) * 4);
  int2*     bpk  = (int2*)alloc(padE * 8);
  float*    dinv = (float*)alloc((size_t)n * 4);
  unsigned* h1s  = (unsigned*)alloc((size_t)n * 32 * 4);
  unsigned* h2s  = (unsigned*)alloc((size_t)n * 8 * 4);

  int gC = (E + CHUNK - 1) / CHUNK;  // 391

  k_zeroC<<<(NS + BLK - 1) / BLK, BLK, 0, stream>>>(cur, NS);
  k_bucket<<<gC, BBLK, 0, stream>>>(src, dst, ew, cur, bpk, n, E, NS);
  k_dinv<<<NS, BLK, 0, stream>>>(bpk, cur, dinv, n);
  k_gemm1<<<(n + 63) / 64, BLK, 0, stream>>>(x, W1, dinv, h1s, n);
  k_agg1s<<<NS, ABLK, 0, stream>>>(dinv, bpk, cur, h1s, b1, W2, h2s, n);
  k_agg2s<<<NS, ABLK, 0, stream>>>(dinv, bpk, cur, h2s, b2, out, n);
}

// Round 13
// 219.999 us; speedup vs baseline: 4.3931x; 4.3931x over previous
//
#include <hip/hip_runtime.h>
#include <cstdint>

#define BLK 256
#define DBLK 512           // k_dinv: 8 waves
#define ABLK 512           // agg kernels: 8 waves/block
#define BBLK 1024          // bucket: 16 waves/block (R7 lesson: occupancy must
                           // come from BLK, not grid — batching needs CHUNK>>NS)
#define EJ 4
#define CHUNK (BBLK * EJ)  // 4096 edges per bucket block, grid 391
#define SLB 6              // slice = 64 nodes
#define SLN 64
#define SCAP 1536          // mean 1024 @ E=1.6M/NS=1563; +16 sigma; 128-aligned
#define NSMAX 1600         // n <= 102400 supported

// Fixed-point scales for integer LDS atomics. R12 HW fact: raw ds_add_f32
// (inline asm, correctly fenced) is ~25x slower than ds_add_u32 on gfx950 —
// FP LDS atomics are slow in HARDWARE, not just compiler lowering (R1/R2's
// CAS theory had right fix, wrong mechanism). int fixed-point is the only
// fast LDS accumulation path. __float2int_rz (not _rn): saves v_rndne per
// feature; truncation bias <= 60 edges * 2^-21 ~= 3e-5, negligible.
#define S1   2097152.0f        // 2^21, layer-1/2 feature accumulators
#define IS1  (1.0f / 2097152.0f)
#define DSC  16777216.0f       // 2^24, degree accumulator
#define IDSC (1.0f / 16777216.0f)

typedef __attribute__((ext_vector_type(8))) short bf16x8;
typedef __attribute__((ext_vector_type(4))) float f32x4;

__device__ inline unsigned short f2bf(float f) {  // RNE
  unsigned u = __float_as_uint(f);
  return (unsigned short)((u + 0x7FFF + ((u >> 16) & 1)) >> 16);
}
__device__ inline float bflo(unsigned u) { return __uint_as_float(u << 16); }
__device__ inline float bfhi(unsigned u) { return __uint_as_float(u & 0xFFFF0000u); }

// ---------------- init per-slice cursors to slice base ----------------
__global__ __launch_bounds__(BLK) void k_zeroC(int* __restrict__ cur, int NS) {
  int s = blockIdx.x * BLK + threadIdx.x;
  if (s < NS) cur[s] = s * SCAP;
}

// ---------------- bucket edges into fixed-capacity slice bins ----------------
// LDS histogram -> one batched reservation per (block,slice) -> LDS-cursor
// scatter. Single LDS array: c[s] is count, then global base, then cursor.
// 16 waves/block so the scattered 8B stores have TLP to hide under.
// bpk[p] = { (dstLocal<<20) | src, ew }   (requires n <= 2^20, dstLocal < 64)
__global__ __launch_bounds__(BBLK) void k_bucket(const int* __restrict__ src,
                                                 const int* __restrict__ dst,
                                                 const float* __restrict__ ew,
                                                 int* __restrict__ cur,
                                                 int2* __restrict__ bpk,
                                                 int n, int E, int NS) {
  __shared__ int c[NSMAX];
  int tid = threadIdx.x;
  for (int i = tid; i < NS; i += BBLK) c[i] = 0;
  __syncthreads();
  int base = blockIdx.x * CHUNK;
  int dloc[EJ];
#pragma unroll
  for (int j = 0; j < EJ; j++) {
    int idx = base + j * BBLK + tid;
    int d = -1;
    if (idx < E) {
      d = dst[idx];
      if ((unsigned)d >= (unsigned)n) d = -1;
    }
    dloc[j] = d;
    if (d >= 0) atomicAdd(&c[d >> SLB], 1);
  }
  __syncthreads();
  for (int s = tid; s < NS; s += BBLK) {
    int cc = c[s];
    if (cc) c[s] = atomicAdd(&cur[s], cc);  // c[s] becomes this block's cursor
  }
  __syncthreads();
#pragma unroll
  for (int j = 0; j < EJ; j++) {
    int idx = base + j * BBLK + tid;
    int d = dloc[j];
    if (d >= 0) {
      int s = d >> SLB;
      int p = atomicAdd(&c[s], 1);
      p = min(max(p, s * SCAP), (s + 1) * SCAP - 1);  // clamp into slice
      int packed = ((d & (SLN - 1)) << 20) | (src[idx] & 0xFFFFF);
      bpk[p] = make_int2(packed, __float_as_int(ew[idx]));
    }
  }
}

// ---------------- per-slice weighted in-degree -> dinv; pad slices ----------
// Pads each slice's edge list to a multiple of 128 with {0,0} dummies
// (dl=0, w=0 -> contributes nothing) so agg loops run maskless/clampless.
__global__ __launch_bounds__(DBLK) void k_dinv(int2* __restrict__ bpk,
                                               int* __restrict__ cur,
                                               float* __restrict__ dinv, int n) {
  __shared__ int wsum[SLN];
  int s = blockIdx.x, tid = threadIdx.x;
  int node0 = s << SLB;
  int e0 = s * SCAP;
  int cnt = min(cur[s], e0 + SCAP) - e0;
  int cntP = min((cnt + 127) & ~127, SCAP);  // SCAP is 128-aligned
  if (tid < SLN) wsum[tid] = 0;
  for (int e = cnt + tid; e < cntP; e += DBLK) bpk[e0 + e] = make_int2(0, 0);
  if (tid == 0) cur[s] = e0 + cntP;
  __syncthreads();
  for (int e = e0 + tid; e < e0 + cnt; e += DBLK) {
    int2 pk = bpk[e];
    atomicAdd(&wsum[(unsigned)pk.x >> 20],
              __float2int_rz(__int_as_float(pk.y) * DSC));
  }
  __syncthreads();
  if (tid < SLN && node0 + tid < n)
    dinv[node0 + tid] = rsqrtf(1.0f + wsum[tid] * IDSC);  // deg >= 1 (self loop)
}

// ---------------- GEMM1 (MFMA bf16x3): h1s = dinv * (x @ W1), fp32-faithful --
// bf16x3 split: x=xh+xl, W=Wh+Wl; h ~= xh@Wh + xl@Wh + xh@Wl (residual ~2^-17
// rel). Block = 64 rows x 64 cols, 4 waves x 16 rows, K=128 = 4 ksteps.
// Frag layout (m89/m97-verified): A/B lane&15 = row/col, 8 k-contig at
// (lane>>4)*8; C/D col=lane&15, row=(lane>>4)*4+reg.
__device__ inline void splitpk(float a, float b, unsigned& h, unsigned& l) {
  unsigned short ha = f2bf(a), hb = f2bf(b);
  h = (unsigned)ha | ((unsigned)hb << 16);
  float ra = a - __uint_as_float((unsigned)ha << 16);
  float rb = b - __uint_as_float((unsigned)hb << 16);
  l = (unsigned)f2bf(ra) | ((unsigned)f2bf(rb) << 16);
}

__global__ __launch_bounds__(BLK) void k_gemm1(const float* __restrict__ x,
                                               const float* __restrict__ W,
                                               const float* __restrict__ dinv,
                                               unsigned* __restrict__ h1s, int n) {
  __shared__ unsigned Wh[4][4][64][4];  // [kstep][coltile][lane][dword]
  __shared__ unsigned Wl[4][4][64][4];
  int tid = threadIdx.x;
  for (int i = tid; i < 4096; i += BLK) {
    int dw = i & 3, lane = (i >> 2) & 63, ct = (i >> 8) & 3, ks = i >> 10;
    int col = ct * 16 + (lane & 15);
    int kb = ks * 32 + ((lane >> 4) << 3) + dw * 2;
    unsigned h, l;
    splitpk(W[kb * 64 + col], W[(kb + 1) * 64 + col], h, l);
    Wh[ks][ct][lane][dw] = h;
    Wl[ks][ct][lane][dw] = l;
  }
  __syncthreads();

  int w = tid >> 6, l = tid & 63;
  int rowA = blockIdx.x * 64 + w * 16 + (l & 15);    // row this lane LOADS
  int rowAc = min(rowA, n - 1);
  int kg = l >> 4;
  const float4* xr = (const float4*)(x + (size_t)rowAc * 128);

  f32x4 acc[4];
#pragma unroll
  for (int ct = 0; ct < 4; ct++) acc[ct] = (f32x4){0.f, 0.f, 0.f, 0.f};

  union Frag { unsigned u[4]; bf16x8 s; };
#pragma unroll
  for (int ks = 0; ks < 4; ks++) {
    float4 f0 = xr[ks * 8 + kg * 2];
    float4 f1 = xr[ks * 8 + kg * 2 + 1];
    Frag Ah, Al;
    splitpk(f0.x, f0.y, Ah.u[0], Al.u[0]);
    splitpk(f0.z, f0.w, Ah.u[1], Al.u[1]);
    splitpk(f1.x, f1.y, Ah.u[2], Al.u[2]);
    splitpk(f1.z, f1.w, Ah.u[3], Al.u[3]);
#pragma unroll
    for (int ct = 0; ct < 4; ct++) {
      Frag Bh, Bl;
      *(uint4*)Bh.u = *(const uint4*)Wh[ks][ct][l];
      *(uint4*)Bl.u = *(const uint4*)Wl[ks][ct][l];
      acc[ct] = __builtin_amdgcn_mfma_f32_16x16x32_bf16(Ah.s, Bh.s, acc[ct], 0, 0, 0);
      acc[ct] = __builtin_amdgcn_mfma_f32_16x16x32_bf16(Al.s, Bh.s, acc[ct], 0, 0, 0);
      acc[ct] = __builtin_amdgcn_mfma_f32_16x16x32_bf16(Ah.s, Bl.s, acc[ct], 0, 0, 0);
    }
  }

  // epilogue: lane owns col = ct*16 + (l&15), rows (l>>4)*4 + r
  int rbase = blockIdx.x * 64 + w * 16 + (l >> 4) * 4;
  float di[4];
#pragma unroll
  for (int r = 0; r < 4; r++) di[r] = dinv[min(rbase + r, n - 1)];
  int cl = l & 15;
#pragma unroll
  for (int ct = 0; ct < 4; ct++) {
#pragma unroll
    for (int r = 0; r < 4; r++) {
      float v = acc[ct][r] * di[r];
      float vp = __shfl_xor(v, 1, 64);
      if ((cl & 1) == 0 && rbase + r < n)
        h1s[(size_t)(rbase + r) * 32 + ct * 8 + (cl >> 1)] =
            (unsigned)f2bf(v) | ((unsigned)f2bf(vp) << 16);
    }
  }
}

// ---------------- layer-1: slice-LDS aggregate + bias + ReLU + GEMM2 --------
// Block = slice of 64 nodes, 512 threads. 16 lanes/edge, lane owns a
// dword-pair (uint2 gather); maskless (slices 128-padded by k_dinv).
// Fixed-point int LDS accumulators (native ds_add_u32 — the only fast LDS
// accumulation path on gfx950, R12), two planes, stride 33. rz convert.
#define U1 8
__global__ __launch_bounds__(ABLK) void k_agg1s(const float* __restrict__ dinv,
                                                const int2* __restrict__ bpk,
                                                const int* __restrict__ cur,
                                                const unsigned* __restrict__ h1s,
                                                const float* __restrict__ b1,
                                                const float* __restrict__ W2,
                                                unsigned* __restrict__ h2s, int n) {
  __shared__ int accE[SLN * 33];
  __shared__ int accO[SLN * 33];
  __shared__ float W2s[64 * 16];
  __shared__ float dv[SLN];
  __shared__ float bb[64];
  int tid = threadIdx.x;
  int s = blockIdx.x;
  int node0 = s << SLB;
  int sn = min(SLN, n - node0);
  for (int i = tid; i < SLN * 33; i += ABLK) { accE[i] = 0; accO[i] = 0; }
  for (int i = tid; i < 1024; i += ABLK) W2s[i] = W2[i];
  if (tid < SLN) dv[tid] = (tid < sn) ? dinv[node0 + tid] : 0.f;
  if (tid < 64) bb[tid] = b1[tid];
  int e0 = s * SCAP;
  int cnt = min(cur[s], e0 + SCAP) - e0;  // multiple of 128 (padded)
  __syncthreads();

  int w = tid >> 6;         // wave 0..7
  int g4 = (tid >> 4) & 3;  // edge sub-slot within wave
  int l = tid & 15;         // owns dwords 2l, 2l+1 (features 4l..4l+3)
  const unsigned* hp = h1s + 2 * l;
  for (int base = w * 32; base < cnt; base += 256) {  // 32 edges/wave-iter
    int2 pk[U1];
#pragma unroll
    for (int u = 0; u < U1; u++) pk[u] = bpk[e0 + base + g4 + 4 * u];
    uint2 gg[U1];
#pragma unroll
    for (int u = 0; u < U1; u++)
      gg[u] = *(const uint2*)(hp + (size_t)(unsigned)(pk[u].x & 0xFFFFF) * 32);
#pragma unroll
    for (int u = 0; u < U1; u++) {
      int a = (int)((unsigned)pk[u].x >> 20) * 33 + 2 * l;
      float wt = __int_as_float(pk[u].y) * S1;
      atomicAdd(&accE[a],     __float2int_rz(wt * bflo(gg[u].x)));
      atomicAdd(&accO[a],     __float2int_rz(wt * bfhi(gg[u].x)));
      atomicAdd(&accE[a + 1], __float2int_rz(wt * bflo(gg[u].y)));
      atomicAdd(&accO[a + 1], __float2int_rz(wt * bfhi(gg[u].y)));
    }
  }
  __syncthreads();
  // F1: in-place relu rows: plane[k&1][node*33+(k>>1)] = relu(dv*(acc+self)+b1[k])
  for (int i = tid; i < SLN * 64; i += ABLK) {
    int node = i >> 6, k = i & 63;
    if (node < sn) {
      int v = node0 + node;
      unsigned us = h1s[(size_t)v * 32 + (k >> 1)];  // self (pre-scaled by dinv)
      float self = (k & 1) ? bfhi(us) : bflo(us);
      int* pl = (k & 1) ? accO : accE;
      int idx = node * 33 + (k >> 1);
      float a = pl[idx] * IS1;
      pl[idx] = __float_as_int(fmaxf(dv[node] * (a + self) + bb[k], 0.f));
    }
  }
  __syncthreads();
  // F2: GEMM2, 16 threads per node, 32 nodes per batch; h2s = dinv * (relu @ W2)
  int j = tid & 15;
  for (int nb = 0; nb < SLN; nb += 32) {
    int node = nb + (tid >> 4);  // 0..31
    float p = 0.f;
#pragma unroll
    for (int k = 0; k < 64; k++) {
      float rv = __int_as_float(((k & 1) ? accO : accE)[node * 33 + (k >> 1)]);
      p += rv * W2s[k * 16 + j];
    }
    p *= dv[node];
    float pp = __shfl_xor(p, 1, 64);
    if (node < sn && (j & 1) == 0)
      h2s[(size_t)(node0 + node) * 8 + (j >> 1)] =
          (unsigned)f2bf(p) | ((unsigned)f2bf(pp) << 16);
  }
}

// ---------------- layer-2: slice-LDS aggregate + bias + log_softmax ---------
// 512 threads. 4 lanes/edge, lane owns dword-pair, 4-deep gather pipeline.
// Maskless. Fixed-point int acc (ds_add_u32), stride 17, rz convert.
#define U2 4
__global__ __launch_bounds__(ABLK) void k_agg2s(const float* __restrict__ dinv,
                                                const int2* __restrict__ bpk,
                                                const int* __restrict__ cur,
                                                const unsigned* __restrict__ h2s,
                                                const float* __restrict__ b2,
                                                float* __restrict__ out, int n) {
  __shared__ int acc2[SLN * 17];
  int tid = threadIdx.x;
  int s = blockIdx.x;
  int node0 = s << SLB;
  int sn = min(SLN, n - node0);
  for (int i = tid; i < SLN * 17; i += ABLK) acc2[i] = 0;
  int e0 = s * SCAP;
  int cnt = min(cur[s], e0 + SCAP) - e0;  // multiple of 128 (padded)
  __syncthreads();

  int w = tid >> 6;          // wave 0..7
  int eg = (tid >> 2) & 15;  // edge slot within wave
  int m = tid & 3;           // owns dwords 2m, 2m+1 (features 4m..4m+3)
  const unsigned* hp = h2s + 2 * m;
  for (int base = w * 64; base < cnt; base += 512) {  // 64 edges/wave-iter
    int2 pk[U2];
#pragma unroll
    for (int u = 0; u < U2; u++) pk[u] = bpk[e0 + base + eg + 16 * u];
    uint2 gg[U2];
#pragma unroll
    for (int u = 0; u < U2; u++)
      gg[u] = *(const uint2*)(hp + (size_t)(unsigned)(pk[u].x & 0xFFFFF) * 8);
#pragma unroll
    for (int u = 0; u < U2; u++) {
      int a = (int)((unsigned)pk[u].x >> 20) * 17 + 4 * m;
      float wt = __int_as_float(pk[u].y) * S1;
      atomicAdd(&acc2[a],     __float2int_rz(wt * bflo(gg[u].x)));
      atomicAdd(&acc2[a + 1], __float2int_rz(wt * bfhi(gg[u].x)));
      atomicAdd(&acc2[a + 2], __float2int_rz(wt * bflo(gg[u].y)));
      atomicAdd(&acc2[a + 3], __float2int_rz(wt * bfhi(gg[u].y)));
    }
  }
  __syncthreads();
  // finalize: 16 threads per node, 32 nodes/batch, log_softmax in 16-lane group
  int f = tid & 15;
  for (int nb = 0; nb < SLN; nb += 32) {
    int node = nb + (tid >> 4);  // 0..31
    bool ok = node < sn;
    int v = node0 + min(node, sn - 1);
    float val = 0.f;
    if (ok) {
      float di = dinv[v];
      unsigned us = h2s[(size_t)v * 8 + (f >> 1)];  // self (pre-scaled)
      float self = (f & 1) ? bfhi(us) : bflo(us);
      val = di * (acc2[node * 17 + f] * IS1 + self) + b2[f];
    }
    float m2 = val;
    m2 = fmaxf(m2, __shfl_xor(m2, 1, 64));
    m2 = fmaxf(m2, __shfl_xor(m2, 2, 64));
    m2 = fmaxf(m2, __shfl_xor(m2, 4, 64));
    m2 = fmaxf(m2, __shfl_xor(m2, 8, 64));
    float ex = expf(val - m2);
    float ssum = ex;
    ssum += __shfl_xor(ssum, 1, 64);
    ssum += __shfl_xor(ssum, 2, 64);
    ssum += __shfl_xor(ssum, 4, 64);
    ssum += __shfl_xor(ssum, 8, 64);
    if (ok) out[(size_t)v * 16 + f] = val - m2 - logf(ssum);
  }
}

extern "C" void kernel_launch(void* const* d_in, const int* in_sizes, int n_in,
                              void* d_out, int out_size, void* d_ws, size_t ws_size,
                              hipStream_t stream) {
  const float* x  = (const float*)d_in[0];
  const int*   ei = (const int*)d_in[1];   // int32 [2,E]
  const float* ew = (const float*)d_in[2];
  const float* W1 = (const float*)d_in[3];
  const float* b1 = (const float*)d_in[4];
  const float* W2 = (const float*)d_in[5];
  const float* b2 = (const float*)d_in[6];
  float* out = (float*)d_out;

  int n = in_sizes[0] / 128;
  int E = in_sizes[2];
  const int* src = ei;
  const int* dst = ei + E;

  int NS = ((n - 1) >> SLB) + 1;  // 1563 for n=100k
  size_t padE = (size_t)NS * SCAP;

  char* wp = (char*)d_ws;
  auto alloc = [&](size_t bytes) -> char* {
    char* r = wp;
    wp += (bytes + 15) & ~(size_t)15;
    return r;
  };
  int*      cur  = (int*)alloc((size_t)(NS + 4) * 4);
  int2*     bpk  = (int2*)alloc(padE * 8);
  float*    dinv = (float*)alloc((size_t)n * 4);
  unsigned* h1s  = (unsigned*)alloc((size_t)n * 32 * 4);
  unsigned* h2s  = (unsigned*)alloc((size_t)n * 8 * 4);

  int gC = (E + CHUNK - 1) / CHUNK;  // 391

  k_zeroC<<<(NS + BLK - 1) / BLK, BLK, 0, stream>>>(cur, NS);
  k_bucket<<<gC, BBLK, 0, stream>>>(src, dst, ew, cur, bpk, n, E, NS);
  k_dinv<<<NS, DBLK, 0, stream>>>(bpk, cur, dinv, n);
  k_gemm1<<<(n + 63) / 64, BLK, 0, stream>>>(x, W1, dinv, h1s, n);
  k_agg1s<<<NS, ABLK, 0, stream>>>(dinv, bpk, cur, h1s, b1, W2, h2s, n);
  k_agg2s<<<NS, ABLK, 0, stream>>>(dinv, bpk, cur, h2s, b2, out, n);
}

// Round 14
// 212.659 us; speedup vs baseline: 4.5447x; 1.0345x over previous
//
#include <hip/hip_runtime.h>
#include <cstdint>

#define BLK 256
#define DBLK 512           // k_dinv: 8 waves
#define ABLK 512           // agg kernels: 8 waves/block
#define BBLK 1024          // bucket: 16 waves/block (R7 lesson: occupancy must
                           // come from BLK, not grid — batching needs CHUNK>>NS)
#define EJ 4
#define CHUNK (BBLK * EJ)  // 4096 edges per bucket block, grid 391
#define SLB 6              // slice = 64 nodes
#define SLN 64
#define SCAP 1536          // mean 1024 @ E=1.6M/NS=1563; +16 sigma; 128-aligned
#define NSMAX 1600         // n <= 102400 supported

// Fixed-point scales for integer LDS atomics. R12 HW fact: raw ds_add_f32
// (inline asm, correctly fenced) is ~25x slower than ds_add_u32 on gfx950 —
// FP LDS atomics are slow in HARDWARE. int fixed-point is the only fast LDS
// accumulation path. __float2int_rz: truncation bias <= 60*2^-21 ~= 3e-5.
#define S1   2097152.0f        // 2^21, layer-1/2 feature accumulators
#define IS1  (1.0f / 2097152.0f)
#define DSC  16777216.0f       // 2^24, degree accumulator
#define IDSC (1.0f / 16777216.0f)

typedef __attribute__((ext_vector_type(8))) short bf16x8;
typedef __attribute__((ext_vector_type(4))) float f32x4;

__device__ inline unsigned short f2bf(float f) {  // RNE
  unsigned u = __float_as_uint(f);
  return (unsigned short)((u + 0x7FFF + ((u >> 16) & 1)) >> 16);
}
__device__ inline float bflo(unsigned u) { return __uint_as_float(u << 16); }
__device__ inline float bfhi(unsigned u) { return __uint_as_float(u & 0xFFFF0000u); }

// split a,b into bf16-hi pair and bf16-lo (residual) pair, packed bf16x2
__device__ inline void splitpk(float a, float b, unsigned& h, unsigned& l) {
  unsigned short ha = f2bf(a), hb = f2bf(b);
  h = (unsigned)ha | ((unsigned)hb << 16);
  float ra = a - __uint_as_float((unsigned)ha << 16);
  float rb = b - __uint_as_float((unsigned)hb << 16);
  l = (unsigned)f2bf(ra) | ((unsigned)f2bf(rb) << 16);
}

// ---------------- init cursors + precompute W1 bf16 hi/lo split -------------
// R14: W split done ONCE here (was per-block in gemm1: 1563x redundant splits
// + 32KB LDS). Layout [ks][ct][lane][dw] flat = i (dw lowest). Folded into the
// init kernel — no extra launch.
__global__ __launch_bounds__(BLK) void k_prep(int* __restrict__ cur,
                                              unsigned* __restrict__ Whg,
                                              unsigned* __restrict__ Wlg,
                                              const float* __restrict__ W,
                                              int NS) {
  int i = blockIdx.x * BLK + threadIdx.x;
  if (i < NS) cur[i] = i * SCAP;
  if (i < 4096) {
    int dw = i & 3, lane = (i >> 2) & 63, ct = (i >> 8) & 3, ks = i >> 10;
    int col = ct * 16 + (lane & 15);
    int kb = ks * 32 + ((lane >> 4) << 3) + dw * 2;
    unsigned h, l;
    splitpk(W[kb * 64 + col], W[(kb + 1) * 64 + col], h, l);
    Whg[i] = h;
    Wlg[i] = l;
  }
}

// ---------------- bucket edges into fixed-capacity slice bins ----------------
// LDS histogram -> one batched reservation per (block,slice) -> LDS-cursor
// scatter. Single LDS array: c[s] is count, then global base, then cursor.
// 16 waves/block so the scattered 8B stores have TLP to hide under.
// bpk[p] = { (dstLocal<<20) | src, ew }   (requires n <= 2^20, dstLocal < 64)
__global__ __launch_bounds__(BBLK) void k_bucket(const int* __restrict__ src,
                                                 const int* __restrict__ dst,
                                                 const float* __restrict__ ew,
                                                 int* __restrict__ cur,
                                                 int2* __restrict__ bpk,
                                                 int n, int E, int NS) {
  __shared__ int c[NSMAX];
  int tid = threadIdx.x;
  for (int i = tid; i < NS; i += BBLK) c[i] = 0;
  __syncthreads();
  int base = blockIdx.x * CHUNK;
  int dloc[EJ];
#pragma unroll
  for (int j = 0; j < EJ; j++) {
    int idx = base + j * BBLK + tid;
    int d = -1;
    if (idx < E) {
      d = dst[idx];
      if ((unsigned)d >= (unsigned)n) d = -1;
    }
    dloc[j] = d;
    if (d >= 0) atomicAdd(&c[d >> SLB], 1);
  }
  __syncthreads();
  for (int s = tid; s < NS; s += BBLK) {
    int cc = c[s];
    if (cc) c[s] = atomicAdd(&cur[s], cc);  // c[s] becomes this block's cursor
  }
  __syncthreads();
#pragma unroll
  for (int j = 0; j < EJ; j++) {
    int idx = base + j * BBLK + tid;
    int d = dloc[j];
    if (d >= 0) {
      int s = d >> SLB;
      int p = atomicAdd(&c[s], 1);
      p = min(max(p, s * SCAP), (s + 1) * SCAP - 1);  // clamp into slice
      int packed = ((d & (SLN - 1)) << 20) | (src[idx] & 0xFFFFF);
      bpk[p] = make_int2(packed, __float_as_int(ew[idx]));
    }
  }
}

// ---------------- per-slice weighted in-degree -> dinv; pad slices ----------
// Pads each slice's edge list to a multiple of 128 with {0,0} dummies
// (dl=0, w=0 -> contributes nothing) so agg loops run maskless/clampless.
__global__ __launch_bounds__(DBLK) void k_dinv(int2* __restrict__ bpk,
                                               int* __restrict__ cur,
                                               float* __restrict__ dinv, int n) {
  __shared__ int wsum[SLN];
  int s = blockIdx.x, tid = threadIdx.x;
  int node0 = s << SLB;
  int e0 = s * SCAP;
  int cnt = min(cur[s], e0 + SCAP) - e0;
  int cntP = min((cnt + 127) & ~127, SCAP);  // SCAP is 128-aligned
  if (tid < SLN) wsum[tid] = 0;
  for (int e = cnt + tid; e < cntP; e += DBLK) bpk[e0 + e] = make_int2(0, 0);
  if (tid == 0) cur[s] = e0 + cntP;
  __syncthreads();
  for (int e = e0 + tid; e < e0 + cnt; e += DBLK) {
    int2 pk = bpk[e];
    atomicAdd(&wsum[(unsigned)pk.x >> 20],
              __float2int_rz(__int_as_float(pk.y) * DSC));
  }
  __syncthreads();
  if (tid < SLN && node0 + tid < n)
    dinv[node0 + tid] = rsqrtf(1.0f + wsum[tid] * IDSC);  // deg >= 1 (self loop)
}

// ---------------- GEMM1 (MFMA bf16x3): h1s = dinv * (x @ W1), fp32-faithful --
// bf16x3 split: x=xh+xl, W=Wh+Wl; h ~= xh@Wh + xl@Wh + xh@Wl (residual ~2^-17
// rel). Block = 64 rows x 64 cols, 4 waves x 16 rows, K=128 = 4 ksteps.
// R14: no LDS, no barriers — B-frags read directly from precomputed Whg/Wlg
// (1KB/instr coalesced, L2-resident). Frag layout (m89/m97-verified):
// A/B lane&15 = row/col, 8 k-contig at (lane>>4)*8; C/D col=lane&15,
// row=(lane>>4)*4+reg.
__global__ __launch_bounds__(BLK) void k_gemm1(const float* __restrict__ x,
                                               const unsigned* __restrict__ Whg,
                                               const unsigned* __restrict__ Wlg,
                                               const float* __restrict__ dinv,
                                               unsigned* __restrict__ h1s, int n) {
  int tid = threadIdx.x;
  int w = tid >> 6, l = tid & 63;
  int rowA = blockIdx.x * 64 + w * 16 + (l & 15);    // row this lane LOADS
  int rowAc = min(rowA, n - 1);
  int kg = l >> 4;
  const float4* xr = (const float4*)(x + (size_t)rowAc * 128);

  f32x4 acc[4];
#pragma unroll
  for (int ct = 0; ct < 4; ct++) acc[ct] = (f32x4){0.f, 0.f, 0.f, 0.f};

  union Frag { unsigned u[4]; bf16x8 s; };
#pragma unroll
  for (int ks = 0; ks < 4; ks++) {
    float4 f0 = xr[ks * 8 + kg * 2];
    float4 f1 = xr[ks * 8 + kg * 2 + 1];
    Frag Ah, Al;
    splitpk(f0.x, f0.y, Ah.u[0], Al.u[0]);
    splitpk(f0.z, f0.w, Ah.u[1], Al.u[1]);
    splitpk(f1.x, f1.y, Ah.u[2], Al.u[2]);
    splitpk(f1.z, f1.w, Ah.u[3], Al.u[3]);
#pragma unroll
    for (int ct = 0; ct < 4; ct++) {
      Frag Bh, Bl;
      *(uint4*)Bh.u = *(const uint4*)&Whg[(((ks * 4 + ct) * 64) + l) * 4];
      *(uint4*)Bl.u = *(const uint4*)&Wlg[(((ks * 4 + ct) * 64) + l) * 4];
      acc[ct] = __builtin_amdgcn_mfma_f32_16x16x32_bf16(Ah.s, Bh.s, acc[ct], 0, 0, 0);
      acc[ct] = __builtin_amdgcn_mfma_f32_16x16x32_bf16(Al.s, Bh.s, acc[ct], 0, 0, 0);
      acc[ct] = __builtin_amdgcn_mfma_f32_16x16x32_bf16(Ah.s, Bl.s, acc[ct], 0, 0, 0);
    }
  }

  // epilogue: lane owns col = ct*16 + (l&15), rows (l>>4)*4 + r
  int rbase = blockIdx.x * 64 + w * 16 + (l >> 4) * 4;
  float di[4];
#pragma unroll
  for (int r = 0; r < 4; r++) di[r] = dinv[min(rbase + r, n - 1)];
  int cl = l & 15;
#pragma unroll
  for (int ct = 0; ct < 4; ct++) {
#pragma unroll
    for (int r = 0; r < 4; r++) {
      float v = acc[ct][r] * di[r];
      float vp = __shfl_xor(v, 1, 64);
      if ((cl & 1) == 0 && rbase + r < n)
        h1s[(size_t)(rbase + r) * 32 + ct * 8 + (cl >> 1)] =
            (unsigned)f2bf(v) | ((unsigned)f2bf(vp) << 16);
    }
  }
}

// ---------------- layer-1: slice-LDS aggregate + bias + ReLU + GEMM2 --------
// Block = slice of 64 nodes, 512 threads. R14: 8 lanes/edge, lane owns a
// uint4 (dwords 4m..4m+3 = feats 8m..8m+7) -> bookkeeping amortizes over 8
// feats (was 4), gather VMEM instrs halve. Maskless (128-padded). Fixed-point
// int LDS accumulators (ds_add_u32), two planes, stride 33. rz convert.
#define U1 4
__global__ __launch_bounds__(ABLK) void k_agg1s(const float* __restrict__ dinv,
                                                const int2* __restrict__ bpk,
                                                const int* __restrict__ cur,
                                                const unsigned* __restrict__ h1s,
                                                const float* __restrict__ b1,
                                                const float* __restrict__ W2,
                                                unsigned* __restrict__ h2s, int n) {
  __shared__ int accE[SLN * 33];
  __shared__ int accO[SLN * 33];
  __shared__ float W2s[64 * 16];
  __shared__ float dv[SLN];
  __shared__ float bb[64];
  int tid = threadIdx.x;
  int s = blockIdx.x;
  int node0 = s << SLB;
  int sn = min(SLN, n - node0);
  for (int i = tid; i < SLN * 33; i += ABLK) { accE[i] = 0; accO[i] = 0; }
  for (int i = tid; i < 1024; i += ABLK) W2s[i] = W2[i];
  if (tid < SLN) dv[tid] = (tid < sn) ? dinv[node0 + tid] : 0.f;
  if (tid < 64) bb[tid] = b1[tid];
  int e0 = s * SCAP;
  int cnt = min(cur[s], e0 + SCAP) - e0;  // multiple of 128 (padded)
  __syncthreads();

  int w = tid >> 6;         // wave 0..7
  int g = (tid >> 3) & 7;   // edge group within wave (8 edges per u)
  int m = tid & 7;          // owns dwords 4m..4m+3 (feats 8m..8m+7)
  const unsigned* hp = h1s + 4 * m;
  for (int base = w * 32; base < cnt; base += 256) {  // 32 edges/wave-iter
    int2 pk[U1];
#pragma unroll
    for (int u = 0; u < U1; u++) pk[u] = bpk[e0 + base + g + 8 * u];
    uint4 gg[U1];
#pragma unroll
    for (int u = 0; u < U1; u++)
      gg[u] = *(const uint4*)(hp + (size_t)(unsigned)(pk[u].x & 0xFFFFF) * 32);
#pragma unroll
    for (int u = 0; u < U1; u++) {
      int a = (int)((unsigned)pk[u].x >> 20) * 33 + 4 * m;
      float wt = __int_as_float(pk[u].y) * S1;
      atomicAdd(&accE[a],     __float2int_rz(wt * bflo(gg[u].x)));
      atomicAdd(&accO[a],     __float2int_rz(wt * bfhi(gg[u].x)));
      atomicAdd(&accE[a + 1], __float2int_rz(wt * bflo(gg[u].y)));
      atomicAdd(&accO[a + 1], __float2int_rz(wt * bfhi(gg[u].y)));
      atomicAdd(&accE[a + 2], __float2int_rz(wt * bflo(gg[u].z)));
      atomicAdd(&accO[a + 2], __float2int_rz(wt * bfhi(gg[u].z)));
      atomicAdd(&accE[a + 3], __float2int_rz(wt * bflo(gg[u].w)));
      atomicAdd(&accO[a + 3], __float2int_rz(wt * bfhi(gg[u].w)));
    }
  }
  __syncthreads();
  // F1: in-place relu rows: plane[k&1][node*33+(k>>1)] = relu(dv*(acc+self)+b1[k])
  for (int i = tid; i < SLN * 64; i += ABLK) {
    int node = i >> 6, k = i & 63;
    if (node < sn) {
      int v = node0 + node;
      unsigned us = h1s[(size_t)v * 32 + (k >> 1)];  // self (pre-scaled by dinv)
      float self = (k & 1) ? bfhi(us) : bflo(us);
      int* pl = (k & 1) ? accO : accE;
      int idx = node * 33 + (k >> 1);
      float a = pl[idx] * IS1;
      pl[idx] = __float_as_int(fmaxf(dv[node] * (a + self) + bb[k], 0.f));
    }
  }
  __syncthreads();
  // F2: GEMM2, 16 threads per node, 32 nodes per batch; h2s = dinv * (relu @ W2)
  int j = tid & 15;
  for (int nb = 0; nb < SLN; nb += 32) {
    int node = nb + (tid >> 4);  // 0..31
    float p = 0.f;
#pragma unroll
    for (int k = 0; k < 64; k++) {
      float rv = __int_as_float(((k & 1) ? accO : accE)[node * 33 + (k >> 1)]);
      p += rv * W2s[k * 16 + j];
    }
    p *= dv[node];
    float pp = __shfl_xor(p, 1, 64);
    if (node < sn && (j & 1) == 0)
      h2s[(size_t)(node0 + node) * 8 + (j >> 1)] =
          (unsigned)f2bf(p) | ((unsigned)f2bf(pp) << 16);
  }
}

// ---------------- layer-2: slice-LDS aggregate + bias + log_softmax ---------
// 512 threads. R14: 2 lanes/edge, lane owns uint4 (dwords 4m..4m+3 = feats
// 8m..8m+7) -> 32 edges per u. Maskless. int acc (ds_add_u32), stride 17.
#define U2 2
__global__ __launch_bounds__(ABLK) void k_agg2s(const float* __restrict__ dinv,
                                                const int2* __restrict__ bpk,
                                                const int* __restrict__ cur,
                                                const unsigned* __restrict__ h2s,
                                                const float* __restrict__ b2,
                                                float* __restrict__ out, int n) {
  __shared__ int acc2[SLN * 17];
  int tid = threadIdx.x;
  int s = blockIdx.x;
  int node0 = s << SLB;
  int sn = min(SLN, n - node0);
  for (int i = tid; i < SLN * 17; i += ABLK) acc2[i] = 0;
  int e0 = s * SCAP;
  int cnt = min(cur[s], e0 + SCAP) - e0;  // multiple of 128 (padded)
  __syncthreads();

  int w = tid >> 6;          // wave 0..7
  int g = (tid >> 1) & 31;   // edge group within wave (32 edges per u)
  int m = tid & 1;           // owns dwords 4m..4m+3 (feats 8m..8m+7)
  const unsigned* hp = h2s + 4 * m;
  for (int base = w * 64; base < cnt; base += 512) {  // 64 edges/wave-iter
    int2 pk[U2];
#pragma unroll
    for (int u = 0; u < U2; u++) pk[u] = bpk[e0 + base + g + 32 * u];
    uint4 gg[U2];
#pragma unroll
    for (int u = 0; u < U2; u++)
      gg[u] = *(const uint4*)(hp + (size_t)(unsigned)(pk[u].x & 0xFFFFF) * 8);
#pragma unroll
    for (int u = 0; u < U2; u++) {
      int a = (int)((unsigned)pk[u].x >> 20) * 17 + 8 * m;
      float wt = __int_as_float(pk[u].y) * S1;
      atomicAdd(&acc2[a],     __float2int_rz(wt * bflo(gg[u].x)));
      atomicAdd(&acc2[a + 1], __float2int_rz(wt * bfhi(gg[u].x)));
      atomicAdd(&acc2[a + 2], __float2int_rz(wt * bflo(gg[u].y)));
      atomicAdd(&acc2[a + 3], __float2int_rz(wt * bfhi(gg[u].y)));
      atomicAdd(&acc2[a + 4], __float2int_rz(wt * bflo(gg[u].z)));
      atomicAdd(&acc2[a + 5], __float2int_rz(wt * bfhi(gg[u].z)));
      atomicAdd(&acc2[a + 6], __float2int_rz(wt * bflo(gg[u].w)));
      atomicAdd(&acc2[a + 7], __float2int_rz(wt * bfhi(gg[u].w)));
    }
  }
  __syncthreads();
  // finalize: 16 threads per node, 32 nodes/batch, log_softmax in 16-lane group
  int f = tid & 15;
  for (int nb = 0; nb < SLN; nb += 32) {
    int node = nb + (tid >> 4);  // 0..31
    bool ok = node < sn;
    int v = node0 + min(node, sn - 1);
    float val = 0.f;
    if (ok) {
      float di = dinv[v];
      unsigned us = h2s[(size_t)v * 8 + (f >> 1)];  // self (pre-scaled)
      float self = (f & 1) ? bfhi(us) : bflo(us);
      val = di * (acc2[node * 17 + f] * IS1 + self) + b2[f];
    }
    float m2 = val;
    m2 = fmaxf(m2, __shfl_xor(m2, 1, 64));
    m2 = fmaxf(m2, __shfl_xor(m2, 2, 64));
    m2 = fmaxf(m2, __shfl_xor(m2, 4, 64));
    m2 = fmaxf(m2, __shfl_xor(m2, 8, 64));
    float ex = expf(val - m2);
    float ssum = ex;
    ssum += __shfl_xor(ssum, 1, 64);
    ssum += __shfl_xor(ssum, 2, 64);
    ssum += __shfl_xor(ssum, 4, 64);
    ssum += __shfl_xor(ssum, 8, 64);
    if (ok) out[(size_t)v * 16 + f] = val - m2 - logf(ssum);
  }
}

extern "C" void kernel_launch(void* const* d_in, const int* in_sizes, int n_in,
                              void* d_out, int out_size, void* d_ws, size_t ws_size,
                              hipStream_t stream) {
  const float* x  = (const float*)d_in[0];
  const int*   ei = (const int*)d_in[1];   // int32 [2,E]
  const float* ew = (const float*)d_in[2];
  const float* W1 = (const float*)d_in[3];
  const float* b1 = (const float*)d_in[4];
  const float* W2 = (const float*)d_in[5];
  const float* b2 = (const float*)d_in[6];
  float* out = (float*)d_out;

  int n = in_sizes[0] / 128;
  int E = in_sizes[2];
  const int* src = ei;
  const int* dst = ei + E;

  int NS = ((n - 1) >> SLB) + 1;  // 1563 for n=100k
  size_t padE = (size_t)NS * SCAP;

  char* wp = (char*)d_ws;
  auto alloc = [&](size_t bytes) -> char* {
    char* r = wp;
    wp += (bytes + 15) & ~(size_t)15;
    return r;
  };
  int*      cur  = (int*)alloc((size_t)(NS + 4) * 4);
  int2*     bpk  = (int2*)alloc(padE * 8);
  float*    dinv = (float*)alloc((size_t)n * 4);
  unsigned* h1s  = (unsigned*)alloc((size_t)n * 32 * 4);
  unsigned* h2s  = (unsigned*)alloc((size_t)n * 8 * 4);
  unsigned* Whg  = (unsigned*)alloc(4096 * 4);
  unsigned* Wlg  = (unsigned*)alloc(4096 * 4);

  int gC = (E + CHUNK - 1) / CHUNK;  // 391
  int gP = (4096 + BLK - 1) / BLK;   // 16 (covers NS=1563 too)

  k_prep<<<gP, BLK, 0, stream>>>(cur, Whg, Wlg, W1, NS);
  k_bucket<<<gC, BBLK, 0, stream>>>(src, dst, ew, cur, bpk, n, E, NS);
  k_dinv<<<NS, DBLK, 0, stream>>>(bpk, cur, dinv, n);
  k_gemm1<<<(n + 63) / 64, BLK, 0, stream>>>(x, Whg, Wlg, dinv, h1s, n);
  k_agg1s<<<NS, ABLK, 0, stream>>>(dinv, bpk, cur, h1s, b1, W2, h2s, n);
  k_agg2s<<<NS, ABLK, 0, stream>>>(dinv, bpk, cur, h2s, b2, out, n);
}